// Round 3
// baseline (398.879 us; speedup 1.0000x reference)
//
#include <hip/hip_runtime.h>
#include <stdint.h>

// ws layout (float offsets)
#define WS_HMUE 0          // [16][64][256] h_mean_ue (mean over p2 = row sums)
#define WS_HMAP 262144     // [16][64][256] h_mean_ap (mean over p1 = col sums)
#define WS_APM  524288     // [16][64] ap_mean
#define WS_UEM  525312     // [16][64] ue_mean
#define WS_STAT 526336     // [2][64][2] (sum, sumsq) per (g,o) — 256 floats
#define WS_Z    526592     // [2][16][64][256] pre-BN z (fp32), 524288 floats

// Kernel 1: H both-axis means + A row means + stats zero-init.
// Blocks 0..1023: one (b,d2) slice of H (256x256 fp32 = 256KB).
// Blocks 1024..1535: A_AP/A_UE row means (4 rows/block, one row per wave).
// Block 1536: zero the BN stats accumulators (re-poisoned to 0xAA each call).
__global__ __launch_bounds__(256) void k_reduce(
    const float* __restrict__ H,
    const float* __restrict__ A_AP, const float* __restrict__ A_UE,
    float* __restrict__ ws)
{
    const int bid = blockIdx.x;
    const int tid = threadIdx.x;
    const int w = tid >> 6;       // wave 0..3
    const int lane = tid & 63;

    __shared__ float lds_row[256];
    __shared__ float lds_col[1024];   // [4 waves][256 cols]

    if (bid < 1024) {
        // slice rows = p1, cols = p2; row-major, row stride 256 floats
        const float4* Hs = (const float4*)(H + (size_t)bid * 65536);
        float c0 = 0.f, c1 = 0.f, c2 = 0.f, c3 = 0.f;

        #pragma unroll 8
        for (int it = 0; it < 64; ++it) {
            const int row = it * 4 + w;
            float4 v = Hs[row * 64 + lane];   // lane covers cols 4*lane..4*lane+3
            c0 += v.x; c1 += v.y; c2 += v.z; c3 += v.w;
            float rs = (v.x + v.y) + (v.z + v.w);
            rs += __shfl_xor(rs, 1);
            rs += __shfl_xor(rs, 2);
            rs += __shfl_xor(rs, 4);
            rs += __shfl_xor(rs, 8);
            rs += __shfl_xor(rs, 16);
            rs += __shfl_xor(rs, 32);
            if (lane == 0) lds_row[row] = rs;
        }
        ((float4*)lds_col)[w * 64 + lane] = make_float4(c0, c1, c2, c3);
        __syncthreads();
        const float cs = lds_col[tid] + lds_col[256 + tid]
                       + lds_col[512 + tid] + lds_col[768 + tid];
        const int oidx = bid * 256 + tid;
        ws[WS_HMAP + oidx] = cs * (1.f / 256.f);           // mean over p1 (rows)
        ws[WS_HMUE + oidx] = lds_row[tid] * (1.f / 256.f); // mean over p2 (cols)
    } else if (bid < 1536) {
        const int m = bid - 1024;     // 0..511
        const int r = m * 4 + w;      // 0..2047: 0..1023 = A_AP, 1024..2047 = A_UE
        const bool is_ap = (r < 1024);
        const float4* src = is_ap ? (const float4*)(A_AP + r * 256)
                                  : (const float4*)(A_UE + (r - 1024) * 256);
        float4 v = src[lane];
        float s = (v.x + v.y) + (v.z + v.w);
        s += __shfl_xor(s, 1);
        s += __shfl_xor(s, 2);
        s += __shfl_xor(s, 4);
        s += __shfl_xor(s, 8);
        s += __shfl_xor(s, 16);
        s += __shfl_xor(s, 32);
        if (lane == 0) {
            if (is_ap) ws[WS_APM + r] = s * (1.f / 256.f);
            else       ws[WS_UEM + (r - 1024)] = s * (1.f / 256.f);
        }
    } else {
        // zero BN stat accumulators (256 floats)
        ws[WS_STAT + tid] = 0.f;
    }
}

// Kernel 2: z[g][b][o][p] = relu( 2*(sum_d Q1[o,d]A[b,d,p] + s2[b,o]) + 0.1*sum_d P1[o,d]hm[b,d,p] )
// block = (g, b, o-tile of 4); thread = p. Also accumulates per-(g,o) BN stats.
__global__ __launch_bounds__(256) void k_z(
    const float* __restrict__ A_AP, const float* __restrict__ A_UE,
    const float* __restrict__ Q1_AP, const float* __restrict__ Q2_AP,
    const float* __restrict__ Q1_UE, const float* __restrict__ Q2_UE,
    const float* __restrict__ P1_AP, const float* __restrict__ P1_UE,
    float* __restrict__ ws)
{
    const int bid = blockIdx.x;
    const int g = bid >> 8;
    const int rem = bid & 255;
    const int b = rem >> 4;
    const int o0 = (rem & 15) * 4;
    const int p = threadIdx.x;
    const int w = p >> 6;
    const int lane = p & 63;

    const float* A  = g ? A_UE : A_AP;
    const float* hm = ws + (g ? WS_HMAP : WS_HMUE);
    const float* am = ws + (g ? WS_APM  : WS_UEM);  // out_ap uses ue_mean; out_ue uses ap_mean
    const float* Q1 = g ? Q1_UE : Q1_AP;
    const float* Q2 = g ? Q2_UE : Q2_AP;
    const float* P1 = g ? P1_UE : P1_AP;
    float* z = ws + WS_Z;
    float* stat = ws + WS_STAT;

    __shared__ float s2[4];
    __shared__ float lds_s[4][4], lds_q[4][4];
    if (threadIdx.x < 4) {
        const float* qr = Q2 + (o0 + threadIdx.x) * 64;
        const float* ar = am + b * 64;
        float s = 0.f;
        #pragma unroll
        for (int d = 0; d < 64; ++d) s += qr[d] * ar[d];
        s2[threadIdx.x] = s;
    }
    __syncthreads();

    float accQ[4] = {0.f, 0.f, 0.f, 0.f};
    float accP[4] = {0.f, 0.f, 0.f, 0.f};
    const float* Ab = A  + (b << 14) + p;   // b*64*256
    const float* hb = hm + (b << 14) + p;

    #pragma unroll 4
    for (int dd = 0; dd < 16; ++dd) {
        const int d0 = dd * 4;
        float a0 = Ab[(d0 + 0) * 256];
        float a1 = Ab[(d0 + 1) * 256];
        float a2 = Ab[(d0 + 2) * 256];
        float a3 = Ab[(d0 + 3) * 256];
        float h0 = hb[(d0 + 0) * 256];
        float h1 = hb[(d0 + 1) * 256];
        float h2 = hb[(d0 + 2) * 256];
        float h3 = hb[(d0 + 3) * 256];
        #pragma unroll
        for (int j = 0; j < 4; ++j) {
            const float4 q  = *(const float4*)(Q1 + (o0 + j) * 64 + d0);
            const float4 pc = *(const float4*)(P1 + (o0 + j) * 64 + d0);
            accQ[j] += q.x * a0 + q.y * a1 + q.z * a2 + q.w * a3;
            accP[j] += pc.x * h0 + pc.y * h1 + pc.z * h2 + pc.w * h3;
        }
    }

    float zv[4];
    #pragma unroll
    for (int j = 0; j < 4; ++j) {
        float v = 2.f * (accQ[j] + s2[j]) + 0.1f * accP[j];
        v = fmaxf(v, 0.f);
        zv[j] = v;
        z[((size_t)(g * 16 + b) * 64 + (o0 + j)) * 256 + p] = v;
    }

    // BN stats: per-o sum & sumsq over this block's 256 p values
    #pragma unroll
    for (int j = 0; j < 4; ++j) {
        float s = zv[j];
        float q = zv[j] * zv[j];
        #pragma unroll
        for (int m = 1; m <= 32; m <<= 1) {
            s += __shfl_xor(s, m);
            q += __shfl_xor(q, m);
        }
        if (lane == 0) { lds_s[w][j] = s; lds_q[w][j] = q; }
    }
    __syncthreads();
    if (threadIdx.x < 4) {
        const int j = threadIdx.x;
        float s = lds_s[0][j] + lds_s[1][j] + lds_s[2][j] + lds_s[3][j];
        float q = lds_q[0][j] + lds_q[1][j] + lds_q[2][j] + lds_q[3][j];
        const int go = g * 64 + (o0 + j);
        atomicAdd(&stat[go * 2 + 0], s);
        atomicAdd(&stat[go * 2 + 1], q);
    }
}

// Kernel 3: streaming BN apply. block covers 1024 contiguous z floats (one o per wave).
__global__ __launch_bounds__(256) void k_bn(
    const float* __restrict__ ws,
    const float* __restrict__ gamma, const float* __restrict__ beta,
    float* __restrict__ out)
{
    const int tid = threadIdx.x;
    const size_t flatw = (size_t)blockIdx.x * 1024 + (tid >> 6) * 256;  // wave's first elem
    const int g = (int)(flatw >> 18);
    const int o = (int)((flatw >> 8) & 63);

    const float* stat = ws + WS_STAT;
    const float s = stat[(g * 64 + o) * 2 + 0];
    const float q = stat[(g * 64 + o) * 2 + 1];
    const float mean = s * (1.f / 4096.f);
    const float var  = q * (1.f / 4096.f) - mean * mean;
    const float rstd = rsqrtf(var + 1e-5f);
    const float scale = rstd * gamma[o];
    const float shift = beta[o] - mean * scale;

    const float4* zp = (const float4*)(ws + WS_Z);
    const size_t i4 = (size_t)blockIdx.x * 256 + tid;
    float4 v = zp[i4];
    float4 r;
    r.x = v.x * scale + shift;
    r.y = v.y * scale + shift;
    r.z = v.z * scale + shift;
    r.w = v.w * scale + shift;
    ((float4*)out)[i4] = r;
}

extern "C" void kernel_launch(void* const* d_in, const int* in_sizes, int n_in,
                              void* d_out, int out_size, void* d_ws, size_t ws_size,
                              hipStream_t stream)
{
    const float* A_AP  = (const float*)d_in[0];
    const float* A_UE  = (const float*)d_in[1];
    const float* H     = (const float*)d_in[2];
    const float* Q1_AP = (const float*)d_in[3];
    const float* Q2_AP = (const float*)d_in[4];
    const float* Q1_UE = (const float*)d_in[5];
    const float* Q2_UE = (const float*)d_in[6];
    const float* P1_AP = (const float*)d_in[7];
    const float* P1_UE = (const float*)d_in[8];
    const float* gamma = (const float*)d_in[9];
    const float* beta  = (const float*)d_in[10];

    float* ws = (float*)d_ws;
    float* out = (float*)d_out;

    hipLaunchKernelGGL(k_reduce, dim3(1537), dim3(256), 0, stream,
                       H, A_AP, A_UE, ws);

    hipLaunchKernelGGL(k_z, dim3(512), dim3(256), 0, stream,
                       A_AP, A_UE, Q1_AP, Q2_AP, Q1_UE, Q2_UE, P1_AP, P1_UE, ws);

    hipLaunchKernelGGL(k_bn, dim3(512), dim3(256), 0, stream,
                       ws, gamma, beta, out);
}